// Round 9
// baseline (596.645 us; speedup 1.0000x reference)
//
#include <hip/hip_runtime.h>
#include <hip/hip_fp16.h>
#include <math.h>

#define NN 100000
#define EE 3200000
#define D 128
#define NB 391        // coarse buckets: node>>8
#define NBLK2 1024    // blocks for hist/scatter passes
#define ECH2 (EE / NBLK2)   // 3125 edges per block (exact)
#define NSTRIP (NN / 32)
#define FS_CAP 14336  // fine_sort LDS staging capacity (56 KB of packed ints)
#define GRID_G2 250   // gemm2 grid (last-ticket fusion constant)

#define SCALE_R 6.0f      // per-round rescale keeps fp8 values ~O(0.3)
#define SCALE_G 512.0f    // post-GEMM1 rescale
#define WSCALE  16.0f     // weight fp8 scale (avoid subnormals)
#define PRE1 (1.0f / (216.0f * WSCALE))            // undo h*6^3, W*16
#define PRE2 (1.0f / (216.0f * SCALE_G * WSCALE))  // undo h2*512*6^3, W*16

typedef float floatx16 __attribute__((ext_vector_type(16)));
typedef float v2f __attribute__((ext_vector_type(2)));

// ---------------- build pass 1: per-block histogram (transposed store) --------
__global__ __launch_bounds__(256) void block_hist(const int* __restrict__ dst,
                                                  int* __restrict__ bh) {
    __shared__ int hist[NB];
    for (int i = threadIdx.x; i < NB; i += 256) hist[i] = 0;
    __syncthreads();
    int e0 = blockIdx.x * ECH2;
    for (int e = e0 + threadIdx.x; e < e0 + ECH2; e += 256)
        atomicAdd(&hist[dst[e] >> 8], 1);
    __syncthreads();
    for (int i = threadIdx.x; i < NB; i += 256)
        bh[i * NBLK2 + blockIdx.x] = hist[i];
}

// ---------------- build pass 2: per-bin exclusive scan over blocks ------------
__global__ __launch_bounds__(256) void bin_scan(int* __restrict__ bh,
                                                int* __restrict__ bintot) {
    __shared__ int ts[256];
    int i = blockIdx.x;
    int t = threadIdx.x;
    int4 v = ((int4*)(bh + i * NBLK2))[t];
    int s = v.x + v.y + v.z + v.w;
    ts[t] = s;
    __syncthreads();
    for (int off = 1; off < 256; off <<= 1) {
        int x = (t >= off) ? ts[t - off] : 0;
        __syncthreads();
        ts[t] += x;
        __syncthreads();
    }
    int run = ts[t] - s;
    int4 o;
    o.x = run; o.y = run + v.x; o.z = o.y + v.y; o.w = o.z + v.z;
    ((int4*)(bh + i * NBLK2))[t] = o;
    if (t == 255) bintot[i] = ts[255];
}

// ---------------- build pass 3: exclusive scan of bin totals -> coff ----------
__global__ __launch_bounds__(512) void tiny_scan(const int* __restrict__ bintot,
                                                 int* __restrict__ coff) {
    __shared__ int s[512];
    int t = threadIdx.x;
    int v = (t < NB) ? bintot[t] : 0;
    s[t] = v;
    __syncthreads();
    for (int off = 1; off < 512; off <<= 1) {
        int x = (t >= off) ? s[t - off] : 0;
        __syncthreads();
        s[t] += x;
        __syncthreads();
    }
    int excl = s[t] - v;
    if (t <= NB) coff[t] = excl;   // coff[NB] == EE
}

// ---------------- build pass 4: scatter with precomputed bases ----------------
// R9: packed 4B entries — (src<<8) | (dst&255). fine_sort needs nothing else
// (bucket slot from low 8 bits, csr entry = src<<7 from the high bits).
// Halves the random-write payload (R8 PMC: WRITE 79.7MB for a 25.6MB payload,
// VALUBusy 1.2% -> pure RMW-inflated write stall).
__global__ __launch_bounds__(256) void scatter2(const int* __restrict__ src,
                                                const int* __restrict__ dst,
                                                const int* __restrict__ bh,
                                                const int* __restrict__ coff,
                                                int* __restrict__ ebuf) {
    __shared__ int base[NB];
    int b = blockIdx.x;
    for (int i = threadIdx.x; i < NB; i += 256)
        base[i] = coff[i] + bh[i * NBLK2 + b];
    __syncthreads();
    int e0 = b * ECH2;
    for (int e = e0 + threadIdx.x; e < e0 + ECH2; e += 256) {
        int d = dst[e];
        int pos = atomicAdd(&base[d >> 8], 1);
        ebuf[pos] = (src[e] << 8) | (d & 255);
    }
}

// ---------------- build pass 5: per-bucket fine sort -> rowptr/norm/csr -------
// csr entries stored pre-shifted <<7 (byte offset of the 128 B fp8 row).
// R8: LDS-staged first read; R9: packed 4B entries double the stage capacity
// to 14336 — every bucket (mean 8192, sigma~90) now stages fully; the global
// overflow path is statistically dead but kept for correctness.
__global__ __launch_bounds__(256) void fine_sort(const int* __restrict__ ebuf,
                                                 const int* __restrict__ coarse_off,
                                                 int* __restrict__ rowptr,
                                                 float* __restrict__ norm,
                                                 int* __restrict__ csr) {
    __shared__ int cnt[256];
    __shared__ int sbuf[256];
    __shared__ int es[FS_CAP];   // 56 KB staging (packed ints)
    int b = blockIdx.x;
    int t = threadIdx.x;
    int e0 = coarse_off[b], e1 = coarse_off[b + 1];
    int n = e1 - e0;
    int nl = n < FS_CAP ? n : FS_CAP;
    int n0 = b << 8;
    cnt[t] = 0;
    __syncthreads();
    for (int i = t; i < nl; i += 256) {
        int pv = ebuf[e0 + i];
        es[i] = pv;
        atomicAdd(&cnt[pv & 255], 1);
    }
    for (int i = FS_CAP + t; i < n; i += 256) {        // overflow tail
        int pv = ebuf[e0 + i];
        atomicAdd(&cnt[pv & 255], 1);
    }
    __syncthreads();
    int myc = cnt[t];
    sbuf[t] = myc;
    __syncthreads();
    for (int off = 1; off < 256; off <<= 1) {
        int x = (t >= off) ? sbuf[t - off] : 0;
        __syncthreads();
        sbuf[t] += x;
        __syncthreads();
    }
    int excl = sbuf[t] - myc;
    int node = n0 + t;
    if (node < NN) {
        rowptr[node] = e0 + excl;
        float dd = (float)myc;
        if (dd < 1.0f) dd = 1.0f;
        norm[node] = rsqrtf(dd);
    }
    cnt[t] = e0 + excl;
    __syncthreads();
    for (int i = t; i < nl; i += 256) {                // from LDS, not global
        int pv = es[i];
        int pos = atomicAdd(&cnt[pv & 255], 1);
        csr[pos] = (pv >> 8) << 7;                     // src*128 byte offset
    }
    for (int i = FS_CAP + t; i < n; i += 256) {        // overflow tail
        int pv = __builtin_nontemporal_load(ebuf + e0 + i);
        int pos = atomicAdd(&cnt[pv & 255], 1);
        csr[pos] = (pv >> 8) << 7;
    }
    if (b == 0 && t == 0) rowptr[NN] = EE;
}

// --- weight convert + transpose to fp8, BOTH weights in one kernel (R8) ------
// blocks 0-31: W1 -> Wt1, blocks 32-63: W2 -> Wt2. Wt8[n*D+k] = fp8(W[k*D+n]*16)
__global__ void conv_w2_fp8(const float* __restrict__ W1, const float* __restrict__ W2,
                            char* __restrict__ Wt1, char* __restrict__ Wt2) {
    int g = blockIdx.x;
    const float* W = (g < 32) ? W1 : W2;
    char* Wt8 = (g < 32) ? Wt1 : Wt2;
    int idx = (g & 31) * 256 + threadIdx.x;
    if (idx < D * D / 2) {
        int n = idx >> 6, k2 = (idx & 63) * 2;
        float a = W[k2 * D + n] * WSCALE;
        float b = W[(k2 + 1) * D + n] * WSCALE;
        int pk = __builtin_amdgcn_cvt_pk_fp8_f32(a, b, 0, 0);
        ((short*)Wt8)[idx] = (short)(pk & 0xffff);
    }
}

// ---------------- convert+scale: g0 = fp8(x * norm) ----------------
__global__ void convert_scale_fp8(const float4* __restrict__ x4, int* __restrict__ g,
                                  const float* __restrict__ norm) {
    int idx = blockIdx.x * 256 + threadIdx.x;   // NN*32 threads, 4 cols each
    if (idx < NN * 32) {
        int row = idx >> 5;
        float n = norm[row];
        float4 v = x4[idx];
        int w = __builtin_amdgcn_cvt_pk_fp8_f32(v.x * n, v.y * n, 0, 0);
        w = __builtin_amdgcn_cvt_pk_fp8_f32(v.z * n, v.w * n, w, 1);
        g[idx] = w;
    }
}

// ---------------- CSR gather on fp8 rows, 4x16 lane layout (FROZEN, R7) -------
// One wave per node. lane = e*16 + c: 4 edge slots x 16 col-chunks of 8B.
// Measured 58.3us at VGPR 24 / occ 70%. R7 PMC: VALUBusy 54, HBM 37%,
// content 7.0 TB/s -> memory-system throughput wall; VALU cuts are exhausted.
// csr index prefetch (R6) + norm hoist (R4) retained. VGPR budget <=32 (R5).
template <int FINAL>
__global__ __launch_bounds__(256) void gather_fp8(const int* __restrict__ rowptr,
                                                  const int* __restrict__ csr,  // <<7
                                                  const char* __restrict__ hs,
                                                  const float* __restrict__ norm,
                                                  char* __restrict__ outv, float post) {
    int node = blockIdx.x * 4 + (threadIdx.x >> 6);
    int lane = threadIdx.x & 63;
    int e = lane >> 4;          // 4 edge slots
    int c = lane & 15;          // 16 col-chunks of 8 B
    int p0 = rowptr[node], p1 = rowptr[node + 1];
    float nrm = norm[node];     // hoisted: latency hides under the edge loop
    v2f acc[4];
#pragma unroll
    for (int i = 0; i < 4; ++i) acc[i] = (v2f)(0.0f);
    int coff8 = c << 3;
    int p = p0 + e;
#define CVT_ACC(v) { \
        acc[0] += __builtin_amdgcn_cvt_pk_f32_fp8((v).x, 0); \
        acc[1] += __builtin_amdgcn_cvt_pk_f32_fp8((v).x, 1); \
        acc[2] += __builtin_amdgcn_cvt_pk_f32_fp8((v).y, 0); \
        acc[3] += __builtin_amdgcn_cvt_pk_f32_fp8((v).y, 1); }
    int s0 = 0, s1 = 0, s2 = 0, s3 = 0;
    if (p + 12 < p1) { s0 = csr[p]; s1 = csr[p + 4]; s2 = csr[p + 8]; s3 = csr[p + 12]; }
    while (p + 12 < p1) {
        int2 v0 = *(const int2*)(hs + (unsigned)s0 + coff8);
        int2 v1 = *(const int2*)(hs + (unsigned)s1 + coff8);
        int2 v2 = *(const int2*)(hs + (unsigned)s2 + coff8);
        int2 v3 = *(const int2*)(hs + (unsigned)s3 + coff8);
        p += 16;
        if (p + 12 < p1) {          // prefetch next iteration's indices
            s0 = csr[p]; s1 = csr[p + 4]; s2 = csr[p + 8]; s3 = csr[p + 12];
        }
        CVT_ACC(v0);
        CVT_ACC(v1);
        CVT_ACC(v2);
        CVT_ACC(v3);
    }
    // 2-deep tail
    for (; p + 4 < p1; p += 8) {
        int t0 = csr[p];
        int t1 = csr[p + 4];
        int2 v0 = *(const int2*)(hs + (unsigned)t0 + coff8);
        int2 v1 = *(const int2*)(hs + (unsigned)t1 + coff8);
        CVT_ACC(v0);
        CVT_ACC(v1);
    }
    if (p < p1) {
        int t0 = csr[p];
        int2 v0 = *(const int2*)(hs + (unsigned)t0 + coff8);
        CVT_ACC(v0);
    }
#undef CVT_ACC
    // reduce over the 4 edge slots: stages 16 and 32
#pragma unroll
    for (int off = 16; off < 64; off <<= 1) {
#pragma unroll
        for (int i = 0; i < 4; ++i) {
            acc[i].x += __shfl_xor(acc[i].x, off, 64);
            acc[i].y += __shfl_xor(acc[i].y, off, 64);
        }
    }
    if (e == 0) {                 // lanes 0..15 write one int2 each = 128 B row
        float m = (FINAL ? nrm : nrm * nrm) * post;
        int2 w;
        w.x = __builtin_amdgcn_cvt_pk_fp8_f32(acc[0].x * m, acc[0].y * m, 0, 0);
        w.x = __builtin_amdgcn_cvt_pk_fp8_f32(acc[1].x * m, acc[1].y * m, w.x, 1);
        w.y = __builtin_amdgcn_cvt_pk_fp8_f32(acc[2].x * m, acc[2].y * m, 0, 0);
        w.y = __builtin_amdgcn_cvt_pk_fp8_f32(acc[3].x * m, acc[3].y * m, w.y, 1);
        *(int2*)(outv + (unsigned)node * 128 + coff8) = w;
    }
}

// ------- fp8 MFMA GEMM1: out_fp8 = fp8(relu(acc*PRE1 + b1) * norm * SCALE_G) --
__global__ __launch_bounds__(256) void gemm1_mfma(const char* __restrict__ H8,
                                                  const char* __restrict__ Wt8,
                                                  const float* __restrict__ b,
                                                  const float* __restrict__ norm,
                                                  char* __restrict__ out8) {
    int lane = threadIdx.x & 63;
    int w = threadIdx.x >> 6;
    int m = lane & 31;
    int q = lane >> 5;
    int col = w * 32 + m;
    long bf[8];
    const long* wp = (const long*)(Wt8 + (size_t)col * D + q * 8);
#pragma unroll
    for (int kc = 0; kc < 8; ++kc) bf[kc] = wp[kc * 2];
    float bc = b[col];
    for (int s = blockIdx.x; s < NSTRIP; s += gridDim.x) {
        int r0 = s * 32;
        floatx16 acc;
#pragma unroll
        for (int i = 0; i < 16; ++i) acc[i] = 0.0f;
        const long* ap = (const long*)(H8 + (size_t)(r0 + m) * D + q * 8);
#pragma unroll
        for (int kc = 0; kc < 8; ++kc)
            acc = __builtin_amdgcn_mfma_f32_32x32x16_fp8_fp8(ap[kc * 2], bf[kc], acc, 0, 0, 0);
#pragma unroll
        for (int r = 0; r < 16; ++r) {
            int row = r0 + (r & 3) + 8 * (r >> 2) + 4 * q;
            float v = fmaxf(acc[r] * PRE1 + bc, 0.0f) * norm[row] * SCALE_G;
            int pk = __builtin_amdgcn_cvt_pk_fp8_f32(v, v, 0, 0);
            out8[(size_t)row * D + col] = (char)(pk & 0xff);
        }
    }
}

// ------- fp8 MFMA GEMM2 + fused final MLP (R8: last-ticket pattern) -----------
__global__ __launch_bounds__(256) void gemm2_mfma_colsum(const char* __restrict__ H8,
                                                         const char* __restrict__ Wt8,
                                                         const float* __restrict__ b,
                                                         float* __restrict__ colsum,
                                                         int* __restrict__ done,
                                                         const float* __restrict__ Wf1,
                                                         const float* __restrict__ bf1,
                                                         const float* __restrict__ Wf2,
                                                         const float* __restrict__ bf2,
                                                         float* __restrict__ out) {
    int lane = threadIdx.x & 63;
    int w = threadIdx.x >> 6;
    int m = lane & 31;
    int q = lane >> 5;
    int col = w * 32 + m;
    long bf[8];
    const long* wp = (const long*)(Wt8 + (size_t)col * D + q * 8);
#pragma unroll
    for (int kc = 0; kc < 8; ++kc) bf[kc] = wp[kc * 2];
    float bc = b[col];
    float csum = 0.0f;
    for (int s = blockIdx.x; s < NSTRIP; s += gridDim.x) {
        int r0 = s * 32;
        floatx16 acc;
#pragma unroll
        for (int i = 0; i < 16; ++i) acc[i] = 0.0f;
        const long* ap = (const long*)(H8 + (size_t)(r0 + m) * D + q * 8);
#pragma unroll
        for (int kc = 0; kc < 8; ++kc)
            acc = __builtin_amdgcn_mfma_f32_32x32x16_fp8_fp8(ap[kc * 2], bf[kc], acc, 0, 0, 0);
#pragma unroll
        for (int r = 0; r < 16; ++r) csum += fmaxf(acc[r] * PRE2 + bc, 0.0f);
    }
    csum += __shfl_down(csum, 32);
    if (lane < 32) atomicAdd(&colsum[col], csum);

    // ---- last-ticket: one block runs the final MLP ----
    __threadfence();                         // release colsum adds
    __shared__ int isLast;
    if (threadIdx.x == 0)
        isLast = (atomicAdd(done, 1) == GRID_G2 - 1);
    __syncthreads();
    if (!isLast) return;

    __shared__ float hg[D];
    __shared__ float red[D];
    int j = threadIdx.x;
    if (j < D) hg[j] = atomicAdd(&colsum[j], 0.0f) * (1.0f / (float)NN);
    __syncthreads();
    if (j < D) {
        float acc2 = bf1[j];
#pragma unroll 16
        for (int k = 0; k < D; ++k)
            acc2 = fmaf(hg[k], Wf1[k * D + j], acc2);
        acc2 = fmaxf(acc2, 0.0f);
        red[j] = acc2 * Wf2[j];
    }
    __syncthreads();
    for (int s = 64; s > 0; s >>= 1) {
        if (j < s) red[j] += red[j + s];
        __syncthreads();
    }
    if (j == 0) {
        float o = red[0] + bf2[0];
        o = fmaxf(o, 0.0f);
        out[0] = 1.0f / (1.0f + expf(-o));
    }
}

// ---------------- launch ------------------------------------------------------
extern "C" void kernel_launch(void* const* d_in, const int* in_sizes, int n_in,
                              void* d_out, int out_size, void* d_ws, size_t ws_size,
                              hipStream_t stream) {
    const float* x   = (const float*)d_in[0];
    const int*   src = (const int*)d_in[1];
    const int*   dst = (const int*)d_in[2];
    const float* W1  = (const float*)d_in[3];
    const float* b1  = (const float*)d_in[4];
    const float* W2  = (const float*)d_in[5];
    const float* b2  = (const float*)d_in[6];
    const float* Wf1 = (const float*)d_in[7];
    const float* bf1 = (const float*)d_in[8];
    const float* Wf2 = (const float*)d_in[9];
    const float* bf2 = (const float*)d_in[10];
    float* out = (float*)d_out;

    char* ws = (char*)d_ws;
    constexpr size_t OFF_BT   = 0;                              // NB ints
    constexpr size_t OFF_CO   = 2048;                           // NB+1 ints
    constexpr size_t OFF_CS   = 4096;                           // colsum (+done ctr)
    constexpr size_t OFF_WT1  = 8192;                           // 16 KB fp8
    constexpr size_t OFF_WT2  = OFF_WT1 + 16384;
    constexpr size_t OFF_RP   = OFF_WT2 + 16384;                // NN+1 ints
    constexpr size_t OFF_NORM = OFF_RP + 400128;
    constexpr size_t OFF_BH   = OFF_NORM + 400128;              // NB*NBLK2 ints (1.6 MB)
    constexpr size_t OFF_EBUF = OFF_BH + (size_t)NB * NBLK2 * 4;// EE ints (12.8 MB, packed)
    constexpr size_t OFF_CSR  = OFF_EBUF + (size_t)EE * 8;      // EE ints (12.8 MB)
    constexpr size_t OFF_A8   = OFF_CSR + (size_t)EE * 4;       // NN*D fp8 (12.8 MB)
    constexpr size_t OFF_B8   = OFF_A8 + (size_t)NN * D;        // NN*D fp8
    int*    bintot = (int*)(ws + OFF_BT);
    int*    coff   = (int*)(ws + OFF_CO);
    float*  colsum = (float*)(ws + OFF_CS);
    int*    done   = (int*)(ws + OFF_CS + 512);                 // ticket counter
    char*   Wt1    = ws + OFF_WT1;
    char*   Wt2    = ws + OFF_WT2;
    int*    rowptr = (int*)(ws + OFF_RP);
    float*  norm   = (float*)(ws + OFF_NORM);
    int*    bh     = (int*)(ws + OFF_BH);
    int*    ebuf   = (int*)(ws + OFF_EBUF);
    int*    csr    = (int*)(ws + OFF_CSR);
    char*   bufA8  = ws + OFF_A8;
    char*   bufB8  = ws + OFF_B8;

    const int nT = 256;
    const int gridC = (NN * 32 + nT - 1) / nT;
    const int gridG = NN / 4;   // one wave per node, 4 waves/block

    // ---- CSR build + norm (no global atomics) ----
    block_hist<<<NBLK2, 256, 0, stream>>>(dst, bh);
    bin_scan<<<NB, 256, 0, stream>>>(bh, bintot);
    tiny_scan<<<1, 512, 0, stream>>>(bintot, coff);
    scatter2<<<NBLK2, 256, 0, stream>>>(src, dst, bh, coff, ebuf);
    fine_sort<<<NB, 256, 0, stream>>>(ebuf, coff, rowptr, norm, csr);

    // ---- weight prep (fp8, transposed, x16), both weights in one kernel ----
    conv_w2_fp8<<<64, 256, 0, stream>>>(W1, W2, Wt1, Wt2);

    // ---- propagation block 1 (fp8 rows, cumulative x6 per round) ----
    convert_scale_fp8<<<gridC, nT, 0, stream>>>((const float4*)x, (int*)bufA8, norm);
    gather_fp8<0><<<gridG, 256, 0, stream>>>(rowptr, csr, bufA8, norm, bufB8, SCALE_R);
    gather_fp8<0><<<gridG, 256, 0, stream>>>(rowptr, csr, bufB8, norm, bufA8, SCALE_R);
    gather_fp8<1><<<gridG, 256, 0, stream>>>(rowptr, csr, bufA8, norm, bufB8, SCALE_R);
    // bufB8 = h * 216 (fp8)

    // ---- g = fp8(relu(h @ W1 + b1) * norm * SCALE_G) : B -> A (fp8 MFMA) ----
    gemm1_mfma<<<625, 256, 0, stream>>>(bufB8, Wt1, b1, norm, bufA8);

    // ---- propagation block 2 ----
    gather_fp8<0><<<gridG, 256, 0, stream>>>(rowptr, csr, bufA8, norm, bufB8, SCALE_R);
    gather_fp8<0><<<gridG, 256, 0, stream>>>(rowptr, csr, bufB8, norm, bufA8, SCALE_R);
    gather_fp8<1><<<gridG, 256, 0, stream>>>(rowptr, csr, bufA8, norm, bufB8, SCALE_R);
    // bufB8 = h2 * 512 * 216 (fp8)

    // ---- colsum of relu(h2 @ W2 + b2) + fused final MLP (fp8 MFMA) ----
    hipMemsetAsync(colsum, 0, 768, stream);   // zeroes colsum[128] + done ctr
    gemm2_mfma_colsum<<<GRID_G2, 256, 0, stream>>>(bufB8, Wt2, b2, colsum, done,
                                                   Wf1, bf1, Wf2, bf2, out);
}

// Round 10
// 585.382 us; speedup vs baseline: 1.0192x; 1.0192x over previous
//
#include <hip/hip_runtime.h>
#include <hip/hip_fp16.h>
#include <math.h>

#define NN 100000
#define EE 3200000
#define D 128
#define NB 391        // coarse buckets: node>>8
#define NBLK2 256     // R10: 1024 -> 256. Segments 32B -> 128B (line-touch fix)
#define ECH2 (EE / NBLK2)   // 12500 edges per block (exact)
#define NSTRIP (NN / 32)
#define FS_CAP 14336  // fine_sort LDS staging capacity (56 KB of packed ints)
#define GRID_G2 250   // gemm2 grid (last-ticket fusion constant)

#define SCALE_R 6.0f      // per-round rescale keeps fp8 values ~O(0.3)
#define SCALE_G 512.0f    // post-GEMM1 rescale
#define WSCALE  16.0f     // weight fp8 scale (avoid subnormals)
#define PRE1 (1.0f / (216.0f * WSCALE))            // undo h*6^3, W*16
#define PRE2 (1.0f / (216.0f * SCALE_G * WSCALE))  // undo h2*512*6^3, W*16

typedef float floatx16 __attribute__((ext_vector_type(16)));
typedef float v2f __attribute__((ext_vector_type(2)));

// ---------------- build pass 1: per-block histogram (transposed store) --------
__global__ __launch_bounds__(256) void block_hist(const int* __restrict__ dst,
                                                  int* __restrict__ bh) {
    __shared__ int hist[NB];
    for (int i = threadIdx.x; i < NB; i += 256) hist[i] = 0;
    __syncthreads();
    int e0 = blockIdx.x * ECH2;
    for (int e = e0 + threadIdx.x; e < e0 + ECH2; e += 256)
        atomicAdd(&hist[dst[e] >> 8], 1);
    __syncthreads();
    for (int i = threadIdx.x; i < NB; i += 256)
        bh[i * NBLK2 + blockIdx.x] = hist[i];
}

// ---------------- build pass 2: per-bin exclusive scan over blocks ------------
// R10: NBLK2=256 -> one element per thread, standard Hillis-Steele.
__global__ __launch_bounds__(256) void bin_scan(int* __restrict__ bh,
                                                int* __restrict__ bintot) {
    __shared__ int ts[256];
    int i = blockIdx.x;      // bucket
    int t = threadIdx.x;     // block index within bucket
    int v = bh[i * NBLK2 + t];
    ts[t] = v;
    __syncthreads();
    for (int off = 1; off < 256; off <<= 1) {
        int x = (t >= off) ? ts[t - off] : 0;
        __syncthreads();
        ts[t] += x;
        __syncthreads();
    }
    bh[i * NBLK2 + t] = ts[t] - v;   // exclusive
    if (t == 255) bintot[i] = ts[255];
}

// ---------------- build pass 3: exclusive scan of bin totals -> coff ----------
__global__ __launch_bounds__(512) void tiny_scan(const int* __restrict__ bintot,
                                                 int* __restrict__ coff) {
    __shared__ int s[512];
    int t = threadIdx.x;
    int v = (t < NB) ? bintot[t] : 0;
    s[t] = v;
    __syncthreads();
    for (int off = 1; off < 512; off <<= 1) {
        int x = (t >= off) ? s[t - off] : 0;
        __syncthreads();
        s[t] += x;
        __syncthreads();
    }
    int excl = s[t] - v;
    if (t <= NB) coff[t] = excl;   // coff[NB] == EE
}

// ---------------- build pass 4: scatter with precomputed bases ----------------
// Packed 4B entries (R9): (src<<8) | (dst&255). R10: NBLK2=256 makes each
// (bucket,block) segment ~32 edges = 128B, so 7/8 of the random stores hit a
// line this block already owns in L2 (write-allocate paid once per line, one
// writeback when full). At NBLK2=1024 segments were 32B -> every line shared
// across blocks/XCDs -> RMW ping-pong (R8/R9 PMC: WRITE 5.5x payload,
// VALUBusy 1.2%).
__global__ __launch_bounds__(256) void scatter2(const int* __restrict__ src,
                                                const int* __restrict__ dst,
                                                const int* __restrict__ bh,
                                                const int* __restrict__ coff,
                                                int* __restrict__ ebuf) {
    __shared__ int base[NB];
    int b = blockIdx.x;
    for (int i = threadIdx.x; i < NB; i += 256)
        base[i] = coff[i] + bh[i * NBLK2 + b];
    __syncthreads();
    int e0 = b * ECH2;
    for (int e = e0 + threadIdx.x; e < e0 + ECH2; e += 256) {
        int d = dst[e];
        int pos = atomicAdd(&base[d >> 8], 1);
        ebuf[pos] = (src[e] << 8) | (d & 255);
    }
}

// ---------------- build pass 5: per-bucket fine sort -> rowptr/norm/csr -------
// csr entries stored pre-shifted <<7 (byte offset of the 128 B fp8 row).
// R8: LDS-staged first read; R9: packed 4B entries — stage capacity 14336,
// every bucket (mean 8184, sigma~90) stages fully; overflow path statistically
// dead but kept for correctness.
__global__ __launch_bounds__(256) void fine_sort(const int* __restrict__ ebuf,
                                                 const int* __restrict__ coarse_off,
                                                 int* __restrict__ rowptr,
                                                 float* __restrict__ norm,
                                                 int* __restrict__ csr) {
    __shared__ int cnt[256];
    __shared__ int sbuf[256];
    __shared__ int es[FS_CAP];   // 56 KB staging (packed ints)
    int b = blockIdx.x;
    int t = threadIdx.x;
    int e0 = coarse_off[b], e1 = coarse_off[b + 1];
    int n = e1 - e0;
    int nl = n < FS_CAP ? n : FS_CAP;
    int n0 = b << 8;
    cnt[t] = 0;
    __syncthreads();
    for (int i = t; i < nl; i += 256) {
        int pv = ebuf[e0 + i];
        es[i] = pv;
        atomicAdd(&cnt[pv & 255], 1);
    }
    for (int i = FS_CAP + t; i < n; i += 256) {        // overflow tail
        int pv = ebuf[e0 + i];
        atomicAdd(&cnt[pv & 255], 1);
    }
    __syncthreads();
    int myc = cnt[t];
    sbuf[t] = myc;
    __syncthreads();
    for (int off = 1; off < 256; off <<= 1) {
        int x = (t >= off) ? sbuf[t - off] : 0;
        __syncthreads();
        sbuf[t] += x;
        __syncthreads();
    }
    int excl = sbuf[t] - myc;
    int node = n0 + t;
    if (node < NN) {
        rowptr[node] = e0 + excl;
        float dd = (float)myc;
        if (dd < 1.0f) dd = 1.0f;
        norm[node] = rsqrtf(dd);
    }
    cnt[t] = e0 + excl;
    __syncthreads();
    for (int i = t; i < nl; i += 256) {                // from LDS, not global
        int pv = es[i];
        int pos = atomicAdd(&cnt[pv & 255], 1);
        csr[pos] = (pv >> 8) << 7;                     // src*128 byte offset
    }
    for (int i = FS_CAP + t; i < n; i += 256) {        // overflow tail
        int pv = __builtin_nontemporal_load(ebuf + e0 + i);
        int pos = atomicAdd(&cnt[pv & 255], 1);
        csr[pos] = (pv >> 8) << 7;
    }
    if (b == 0 && t == 0) rowptr[NN] = EE;
}

// --- weight convert + transpose to fp8, BOTH weights in one kernel (R8) ------
// blocks 0-31: W1 -> Wt1, blocks 32-63: W2 -> Wt2. Wt8[n*D+k] = fp8(W[k*D+n]*16)
__global__ void conv_w2_fp8(const float* __restrict__ W1, const float* __restrict__ W2,
                            char* __restrict__ Wt1, char* __restrict__ Wt2) {
    int g = blockIdx.x;
    const float* W = (g < 32) ? W1 : W2;
    char* Wt8 = (g < 32) ? Wt1 : Wt2;
    int idx = (g & 31) * 256 + threadIdx.x;
    if (idx < D * D / 2) {
        int n = idx >> 6, k2 = (idx & 63) * 2;
        float a = W[k2 * D + n] * WSCALE;
        float b = W[(k2 + 1) * D + n] * WSCALE;
        int pk = __builtin_amdgcn_cvt_pk_fp8_f32(a, b, 0, 0);
        ((short*)Wt8)[idx] = (short)(pk & 0xffff);
    }
}

// ---------------- convert+scale: g0 = fp8(x * norm) ----------------
__global__ void convert_scale_fp8(const float4* __restrict__ x4, int* __restrict__ g,
                                  const float* __restrict__ norm) {
    int idx = blockIdx.x * 256 + threadIdx.x;   // NN*32 threads, 4 cols each
    if (idx < NN * 32) {
        int row = idx >> 5;
        float n = norm[row];
        float4 v = x4[idx];
        int w = __builtin_amdgcn_cvt_pk_fp8_f32(v.x * n, v.y * n, 0, 0);
        w = __builtin_amdgcn_cvt_pk_fp8_f32(v.z * n, v.w * n, w, 1);
        g[idx] = w;
    }
}

// ---------------- CSR gather on fp8 rows, 4x16 lane layout (FROZEN, R7) -------
// One wave per node. lane = e*16 + c: 4 edge slots x 16 col-chunks of 8B.
// Measured 58.3us at VGPR 24 / occ 70%. R7 PMC: VALUBusy 54, HBM 37%,
// content 7.0 TB/s -> memory-system throughput wall; VALU cuts are exhausted.
// csr index prefetch (R6) + norm hoist (R4) retained. VGPR budget <=32 (R5).
template <int FINAL>
__global__ __launch_bounds__(256) void gather_fp8(const int* __restrict__ rowptr,
                                                  const int* __restrict__ csr,  // <<7
                                                  const char* __restrict__ hs,
                                                  const float* __restrict__ norm,
                                                  char* __restrict__ outv, float post) {
    int node = blockIdx.x * 4 + (threadIdx.x >> 6);
    int lane = threadIdx.x & 63;
    int e = lane >> 4;          // 4 edge slots
    int c = lane & 15;          // 16 col-chunks of 8 B
    int p0 = rowptr[node], p1 = rowptr[node + 1];
    float nrm = norm[node];     // hoisted: latency hides under the edge loop
    v2f acc[4];
#pragma unroll
    for (int i = 0; i < 4; ++i) acc[i] = (v2f)(0.0f);
    int coff8 = c << 3;
    int p = p0 + e;
#define CVT_ACC(v) { \
        acc[0] += __builtin_amdgcn_cvt_pk_f32_fp8((v).x, 0); \
        acc[1] += __builtin_amdgcn_cvt_pk_f32_fp8((v).x, 1); \
        acc[2] += __builtin_amdgcn_cvt_pk_f32_fp8((v).y, 0); \
        acc[3] += __builtin_amdgcn_cvt_pk_f32_fp8((v).y, 1); }
    int s0 = 0, s1 = 0, s2 = 0, s3 = 0;
    if (p + 12 < p1) { s0 = csr[p]; s1 = csr[p + 4]; s2 = csr[p + 8]; s3 = csr[p + 12]; }
    while (p + 12 < p1) {
        int2 v0 = *(const int2*)(hs + (unsigned)s0 + coff8);
        int2 v1 = *(const int2*)(hs + (unsigned)s1 + coff8);
        int2 v2 = *(const int2*)(hs + (unsigned)s2 + coff8);
        int2 v3 = *(const int2*)(hs + (unsigned)s3 + coff8);
        p += 16;
        if (p + 12 < p1) {          // prefetch next iteration's indices
            s0 = csr[p]; s1 = csr[p + 4]; s2 = csr[p + 8]; s3 = csr[p + 12];
        }
        CVT_ACC(v0);
        CVT_ACC(v1);
        CVT_ACC(v2);
        CVT_ACC(v3);
    }
    // 2-deep tail
    for (; p + 4 < p1; p += 8) {
        int t0 = csr[p];
        int t1 = csr[p + 4];
        int2 v0 = *(const int2*)(hs + (unsigned)t0 + coff8);
        int2 v1 = *(const int2*)(hs + (unsigned)t1 + coff8);
        CVT_ACC(v0);
        CVT_ACC(v1);
    }
    if (p < p1) {
        int t0 = csr[p];
        int2 v0 = *(const int2*)(hs + (unsigned)t0 + coff8);
        CVT_ACC(v0);
    }
#undef CVT_ACC
    // reduce over the 4 edge slots: stages 16 and 32
#pragma unroll
    for (int off = 16; off < 64; off <<= 1) {
#pragma unroll
        for (int i = 0; i < 4; ++i) {
            acc[i].x += __shfl_xor(acc[i].x, off, 64);
            acc[i].y += __shfl_xor(acc[i].y, off, 64);
        }
    }
    if (e == 0) {                 // lanes 0..15 write one int2 each = 128 B row
        float m = (FINAL ? nrm : nrm * nrm) * post;
        int2 w;
        w.x = __builtin_amdgcn_cvt_pk_fp8_f32(acc[0].x * m, acc[0].y * m, 0, 0);
        w.x = __builtin_amdgcn_cvt_pk_fp8_f32(acc[1].x * m, acc[1].y * m, w.x, 1);
        w.y = __builtin_amdgcn_cvt_pk_fp8_f32(acc[2].x * m, acc[2].y * m, 0, 0);
        w.y = __builtin_amdgcn_cvt_pk_fp8_f32(acc[3].x * m, acc[3].y * m, w.y, 1);
        *(int2*)(outv + (unsigned)node * 128 + coff8) = w;
    }
}

// ------- fp8 MFMA GEMM1: out_fp8 = fp8(relu(acc*PRE1 + b1) * norm * SCALE_G) --
__global__ __launch_bounds__(256) void gemm1_mfma(const char* __restrict__ H8,
                                                  const char* __restrict__ Wt8,
                                                  const float* __restrict__ b,
                                                  const float* __restrict__ norm,
                                                  char* __restrict__ out8) {
    int lane = threadIdx.x & 63;
    int w = threadIdx.x >> 6;
    int m = lane & 31;
    int q = lane >> 5;
    int col = w * 32 + m;
    long bf[8];
    const long* wp = (const long*)(Wt8 + (size_t)col * D + q * 8);
#pragma unroll
    for (int kc = 0; kc < 8; ++kc) bf[kc] = wp[kc * 2];
    float bc = b[col];
    for (int s = blockIdx.x; s < NSTRIP; s += gridDim.x) {
        int r0 = s * 32;
        floatx16 acc;
#pragma unroll
        for (int i = 0; i < 16; ++i) acc[i] = 0.0f;
        const long* ap = (const long*)(H8 + (size_t)(r0 + m) * D + q * 8);
#pragma unroll
        for (int kc = 0; kc < 8; ++kc)
            acc = __builtin_amdgcn_mfma_f32_32x32x16_fp8_fp8(ap[kc * 2], bf[kc], acc, 0, 0, 0);
#pragma unroll
        for (int r = 0; r < 16; ++r) {
            int row = r0 + (r & 3) + 8 * (r >> 2) + 4 * q;
            float v = fmaxf(acc[r] * PRE1 + bc, 0.0f) * norm[row] * SCALE_G;
            int pk = __builtin_amdgcn_cvt_pk_fp8_f32(v, v, 0, 0);
            out8[(size_t)row * D + col] = (char)(pk & 0xff);
        }
    }
}

// ------- fp8 MFMA GEMM2 + fused final MLP (R8: last-ticket pattern) -----------
__global__ __launch_bounds__(256) void gemm2_mfma_colsum(const char* __restrict__ H8,
                                                         const char* __restrict__ Wt8,
                                                         const float* __restrict__ b,
                                                         float* __restrict__ colsum,
                                                         int* __restrict__ done,
                                                         const float* __restrict__ Wf1,
                                                         const float* __restrict__ bf1,
                                                         const float* __restrict__ Wf2,
                                                         const float* __restrict__ bf2,
                                                         float* __restrict__ out) {
    int lane = threadIdx.x & 63;
    int w = threadIdx.x >> 6;
    int m = lane & 31;
    int q = lane >> 5;
    int col = w * 32 + m;
    long bf[8];
    const long* wp = (const long*)(Wt8 + (size_t)col * D + q * 8);
#pragma unroll
    for (int kc = 0; kc < 8; ++kc) bf[kc] = wp[kc * 2];
    float bc = b[col];
    float csum = 0.0f;
    for (int s = blockIdx.x; s < NSTRIP; s += gridDim.x) {
        int r0 = s * 32;
        floatx16 acc;
#pragma unroll
        for (int i = 0; i < 16; ++i) acc[i] = 0.0f;
        const long* ap = (const long*)(H8 + (size_t)(r0 + m) * D + q * 8);
#pragma unroll
        for (int kc = 0; kc < 8; ++kc)
            acc = __builtin_amdgcn_mfma_f32_32x32x16_fp8_fp8(ap[kc * 2], bf[kc], acc, 0, 0, 0);
#pragma unroll
        for (int r = 0; r < 16; ++r) csum += fmaxf(acc[r] * PRE2 + bc, 0.0f);
    }
    csum += __shfl_down(csum, 32);
    if (lane < 32) atomicAdd(&colsum[col], csum);

    // ---- last-ticket: one block runs the final MLP ----
    __threadfence();                         // release colsum adds
    __shared__ int isLast;
    if (threadIdx.x == 0)
        isLast = (atomicAdd(done, 1) == GRID_G2 - 1);
    __syncthreads();
    if (!isLast) return;

    __shared__ float hg[D];
    __shared__ float red[D];
    int j = threadIdx.x;
    if (j < D) hg[j] = atomicAdd(&colsum[j], 0.0f) * (1.0f / (float)NN);
    __syncthreads();
    if (j < D) {
        float acc2 = bf1[j];
#pragma unroll 16
        for (int k = 0; k < D; ++k)
            acc2 = fmaf(hg[k], Wf1[k * D + j], acc2);
        acc2 = fmaxf(acc2, 0.0f);
        red[j] = acc2 * Wf2[j];
    }
    __syncthreads();
    for (int s = 64; s > 0; s >>= 1) {
        if (j < s) red[j] += red[j + s];
        __syncthreads();
    }
    if (j == 0) {
        float o = red[0] + bf2[0];
        o = fmaxf(o, 0.0f);
        out[0] = 1.0f / (1.0f + expf(-o));
    }
}

// ---------------- launch ------------------------------------------------------
extern "C" void kernel_launch(void* const* d_in, const int* in_sizes, int n_in,
                              void* d_out, int out_size, void* d_ws, size_t ws_size,
                              hipStream_t stream) {
    const float* x   = (const float*)d_in[0];
    const int*   src = (const int*)d_in[1];
    const int*   dst = (const int*)d_in[2];
    const float* W1  = (const float*)d_in[3];
    const float* b1  = (const float*)d_in[4];
    const float* W2  = (const float*)d_in[5];
    const float* b2  = (const float*)d_in[6];
    const float* Wf1 = (const float*)d_in[7];
    const float* bf1 = (const float*)d_in[8];
    const float* Wf2 = (const float*)d_in[9];
    const float* bf2 = (const float*)d_in[10];
    float* out = (float*)d_out;

    char* ws = (char*)d_ws;
    constexpr size_t OFF_BT   = 0;                              // NB ints
    constexpr size_t OFF_CO   = 2048;                           // NB+1 ints
    constexpr size_t OFF_CS   = 4096;                           // colsum (+done ctr)
    constexpr size_t OFF_WT1  = 8192;                           // 16 KB fp8
    constexpr size_t OFF_WT2  = OFF_WT1 + 16384;
    constexpr size_t OFF_RP   = OFF_WT2 + 16384;                // NN+1 ints
    constexpr size_t OFF_NORM = OFF_RP + 400128;
    constexpr size_t OFF_BH   = OFF_NORM + 400128;              // NB*NBLK2 ints (400 KB)
    constexpr size_t OFF_EBUF = OFF_BH + (size_t)NB * NBLK2 * 4;// EE ints (12.8 MB, packed)
    constexpr size_t OFF_CSR  = OFF_EBUF + (size_t)EE * 8;      // EE ints (12.8 MB)
    constexpr size_t OFF_A8   = OFF_CSR + (size_t)EE * 4;       // NN*D fp8 (12.8 MB)
    constexpr size_t OFF_B8   = OFF_A8 + (size_t)NN * D;        // NN*D fp8
    int*    bintot = (int*)(ws + OFF_BT);
    int*    coff   = (int*)(ws + OFF_CO);
    float*  colsum = (float*)(ws + OFF_CS);
    int*    done   = (int*)(ws + OFF_CS + 512);                 // ticket counter
    char*   Wt1    = ws + OFF_WT1;
    char*   Wt2    = ws + OFF_WT2;
    int*    rowptr = (int*)(ws + OFF_RP);
    float*  norm   = (float*)(ws + OFF_NORM);
    int*    bh     = (int*)(ws + OFF_BH);
    int*    ebuf   = (int*)(ws + OFF_EBUF);
    int*    csr    = (int*)(ws + OFF_CSR);
    char*   bufA8  = ws + OFF_A8;
    char*   bufB8  = ws + OFF_B8;

    const int nT = 256;
    const int gridC = (NN * 32 + nT - 1) / nT;
    const int gridG = NN / 4;   // one wave per node, 4 waves/block

    // ---- CSR build + norm (no global atomics) ----
    block_hist<<<NBLK2, 256, 0, stream>>>(dst, bh);
    bin_scan<<<NB, 256, 0, stream>>>(bh, bintot);
    tiny_scan<<<1, 512, 0, stream>>>(bintot, coff);
    scatter2<<<NBLK2, 256, 0, stream>>>(src, dst, bh, coff, ebuf);
    fine_sort<<<NB, 256, 0, stream>>>(ebuf, coff, rowptr, norm, csr);

    // ---- weight prep (fp8, transposed, x16), both weights in one kernel ----
    conv_w2_fp8<<<64, 256, 0, stream>>>(W1, W2, Wt1, Wt2);

    // ---- propagation block 1 (fp8 rows, cumulative x6 per round) ----
    convert_scale_fp8<<<gridC, nT, 0, stream>>>((const float4*)x, (int*)bufA8, norm);
    gather_fp8<0><<<gridG, 256, 0, stream>>>(rowptr, csr, bufA8, norm, bufB8, SCALE_R);
    gather_fp8<0><<<gridG, 256, 0, stream>>>(rowptr, csr, bufB8, norm, bufA8, SCALE_R);
    gather_fp8<1><<<gridG, 256, 0, stream>>>(rowptr, csr, bufA8, norm, bufB8, SCALE_R);
    // bufB8 = h * 216 (fp8)

    // ---- g = fp8(relu(h @ W1 + b1) * norm * SCALE_G) : B -> A (fp8 MFMA) ----
    gemm1_mfma<<<625, 256, 0, stream>>>(bufB8, Wt1, b1, norm, bufA8);

    // ---- propagation block 2 ----
    gather_fp8<0><<<gridG, 256, 0, stream>>>(rowptr, csr, bufA8, norm, bufB8, SCALE_R);
    gather_fp8<0><<<gridG, 256, 0, stream>>>(rowptr, csr, bufB8, norm, bufA8, SCALE_R);
    gather_fp8<1><<<gridG, 256, 0, stream>>>(rowptr, csr, bufA8, norm, bufB8, SCALE_R);
    // bufB8 = h2 * 512 * 216 (fp8)

    // ---- colsum of relu(h2 @ W2 + b2) + fused final MLP (fp8 MFMA) ----
    hipMemsetAsync(colsum, 0, 768, stream);   // zeroes colsum[128] + done ctr
    gemm2_mfma_colsum<<<GRID_G2, 256, 0, stream>>>(bufB8, Wt2, b2, colsum, done,
                                                   Wf1, bf1, Wf2, bf2, out);
}

// Round 11
// 581.219 us; speedup vs baseline: 1.0265x; 1.0072x over previous
//
#include <hip/hip_runtime.h>
#include <hip/hip_fp16.h>
#include <math.h>

#define NN 100000
#define EE 3200000
#define D 128
#define NB 391        // coarse buckets: node>>8
#define NBLK2 256     // R10: 256 segment-owners -> 128B segments (line-touch fix)
#define ECH2 (EE / NBLK2)   // 12500 edges per block (exact)
#define NSTRIP (NN / 32)
#define FS_CAP 14336  // fine_sort LDS staging capacity (56 KB of packed ints)
#define GRID_G2 250   // gemm2 grid (last-ticket fusion constant)

#define SCALE_R 6.0f      // per-round rescale keeps fp8 values ~O(0.3)
#define SCALE_G 512.0f    // post-GEMM1 rescale
#define WSCALE  16.0f     // weight fp8 scale (avoid subnormals)
#define PRE1 (1.0f / (216.0f * WSCALE))            // undo h*6^3, W*16
#define PRE2 (1.0f / (216.0f * SCALE_G * WSCALE))  // undo h2*512*6^3, W*16

typedef float floatx16 __attribute__((ext_vector_type(16)));
typedef float v2f __attribute__((ext_vector_type(2)));

// ---------------- build pass 1: per-block histogram (transposed store) --------
// R11: 1024 threads/block — R10's 256-block geometry left only 4 waves/CU
// (occupancy 8.8%); 16 waves/block restores TLP at identical segment layout.
__global__ __launch_bounds__(1024) void block_hist(const int* __restrict__ dst,
                                                   int* __restrict__ bh) {
    __shared__ int hist[NB];
    for (int i = threadIdx.x; i < NB; i += 1024) hist[i] = 0;
    __syncthreads();
    int e0 = blockIdx.x * ECH2;
    for (int e = e0 + threadIdx.x; e < e0 + ECH2; e += 1024)
        atomicAdd(&hist[dst[e] >> 8], 1);
    __syncthreads();
    for (int i = threadIdx.x; i < NB; i += 1024)
        bh[i * NBLK2 + blockIdx.x] = hist[i];
}

// ---------------- build pass 2: per-bin exclusive scan over blocks ------------
// NBLK2=256 -> one element per thread, standard Hillis-Steele.
__global__ __launch_bounds__(256) void bin_scan(int* __restrict__ bh,
                                                int* __restrict__ bintot) {
    __shared__ int ts[256];
    int i = blockIdx.x;      // bucket
    int t = threadIdx.x;     // block index within bucket
    int v = bh[i * NBLK2 + t];
    ts[t] = v;
    __syncthreads();
    for (int off = 1; off < 256; off <<= 1) {
        int x = (t >= off) ? ts[t - off] : 0;
        __syncthreads();
        ts[t] += x;
        __syncthreads();
    }
    bh[i * NBLK2 + t] = ts[t] - v;   // exclusive
    if (t == 255) bintot[i] = ts[255];
}

// ---------------- build pass 3: exclusive scan of bin totals -> coff ----------
__global__ __launch_bounds__(512) void tiny_scan(const int* __restrict__ bintot,
                                                 int* __restrict__ coff) {
    __shared__ int s[512];
    int t = threadIdx.x;
    int v = (t < NB) ? bintot[t] : 0;
    s[t] = v;
    __syncthreads();
    for (int off = 1; off < 512; off <<= 1) {
        int x = (t >= off) ? s[t - off] : 0;
        __syncthreads();
        s[t] += x;
        __syncthreads();
    }
    int excl = s[t] - v;
    if (t <= NB) coff[t] = excl;   // coff[NB] == EE
}

// ---------------- build pass 4: scatter with precomputed bases ----------------
// Packed 4B entries (R9): (src<<8) | (dst&255). 128B segments (R10): 7/8 of
// stores hit a line this block owns in L2 (WRITE 71->32MB confirmed R10).
// R11: 1024 threads/block — R10 fixed traffic but dropped to 1024 waves chip-
// wide (occupancy 8.8%, HBM 0.8TB/s, VALU 1.1% = latency-bound). 16 waves/
// block gives 4096 waves at the SAME 256-segment write layout.
__global__ __launch_bounds__(1024) void scatter2(const int* __restrict__ src,
                                                 const int* __restrict__ dst,
                                                 const int* __restrict__ bh,
                                                 const int* __restrict__ coff,
                                                 int* __restrict__ ebuf) {
    __shared__ int base[NB];
    int b = blockIdx.x;
    for (int i = threadIdx.x; i < NB; i += 1024)
        base[i] = coff[i] + bh[i * NBLK2 + b];
    __syncthreads();
    int e0 = b * ECH2;
    for (int e = e0 + threadIdx.x; e < e0 + ECH2; e += 1024) {
        int d = dst[e];
        int pos = atomicAdd(&base[d >> 8], 1);
        ebuf[pos] = (src[e] << 8) | (d & 255);
    }
}

// ---------------- build pass 5: per-bucket fine sort -> rowptr/norm/csr -------
// csr entries stored pre-shifted <<7 (byte offset of the 128 B fp8 row).
// R8: LDS-staged first read; R9: packed 4B entries — stage capacity 14336,
// every bucket (mean 8184, sigma~90) stages fully; overflow path statistically
// dead but kept for correctness.
__global__ __launch_bounds__(256) void fine_sort(const int* __restrict__ ebuf,
                                                 const int* __restrict__ coarse_off,
                                                 int* __restrict__ rowptr,
                                                 float* __restrict__ norm,
                                                 int* __restrict__ csr) {
    __shared__ int cnt[256];
    __shared__ int sbuf[256];
    __shared__ int es[FS_CAP];   // 56 KB staging (packed ints)
    int b = blockIdx.x;
    int t = threadIdx.x;
    int e0 = coarse_off[b], e1 = coarse_off[b + 1];
    int n = e1 - e0;
    int nl = n < FS_CAP ? n : FS_CAP;
    int n0 = b << 8;
    cnt[t] = 0;
    __syncthreads();
    for (int i = t; i < nl; i += 256) {
        int pv = ebuf[e0 + i];
        es[i] = pv;
        atomicAdd(&cnt[pv & 255], 1);
    }
    for (int i = FS_CAP + t; i < n; i += 256) {        // overflow tail
        int pv = ebuf[e0 + i];
        atomicAdd(&cnt[pv & 255], 1);
    }
    __syncthreads();
    int myc = cnt[t];
    sbuf[t] = myc;
    __syncthreads();
    for (int off = 1; off < 256; off <<= 1) {
        int x = (t >= off) ? sbuf[t - off] : 0;
        __syncthreads();
        sbuf[t] += x;
        __syncthreads();
    }
    int excl = sbuf[t] - myc;
    int node = n0 + t;
    if (node < NN) {
        rowptr[node] = e0 + excl;
        float dd = (float)myc;
        if (dd < 1.0f) dd = 1.0f;
        norm[node] = rsqrtf(dd);
    }
    cnt[t] = e0 + excl;
    __syncthreads();
    for (int i = t; i < nl; i += 256) {                // from LDS, not global
        int pv = es[i];
        int pos = atomicAdd(&cnt[pv & 255], 1);
        csr[pos] = (pv >> 8) << 7;                     // src*128 byte offset
    }
    for (int i = FS_CAP + t; i < n; i += 256) {        // overflow tail
        int pv = __builtin_nontemporal_load(ebuf + e0 + i);
        int pos = atomicAdd(&cnt[pv & 255], 1);
        csr[pos] = (pv >> 8) << 7;
    }
    if (b == 0 && t == 0) rowptr[NN] = EE;
}

// --- weight convert + transpose to fp8, BOTH weights in one kernel (R8) ------
// blocks 0-31: W1 -> Wt1, blocks 32-63: W2 -> Wt2. Wt8[n*D+k] = fp8(W[k*D+n]*16)
__global__ void conv_w2_fp8(const float* __restrict__ W1, const float* __restrict__ W2,
                            char* __restrict__ Wt1, char* __restrict__ Wt2) {
    int g = blockIdx.x;
    const float* W = (g < 32) ? W1 : W2;
    char* Wt8 = (g < 32) ? Wt1 : Wt2;
    int idx = (g & 31) * 256 + threadIdx.x;
    if (idx < D * D / 2) {
        int n = idx >> 6, k2 = (idx & 63) * 2;
        float a = W[k2 * D + n] * WSCALE;
        float b = W[(k2 + 1) * D + n] * WSCALE;
        int pk = __builtin_amdgcn_cvt_pk_fp8_f32(a, b, 0, 0);
        ((short*)Wt8)[idx] = (short)(pk & 0xffff);
    }
}

// ---------------- convert+scale: g0 = fp8(x * norm) ----------------
__global__ void convert_scale_fp8(const float4* __restrict__ x4, int* __restrict__ g,
                                  const float* __restrict__ norm) {
    int idx = blockIdx.x * 256 + threadIdx.x;   // NN*32 threads, 4 cols each
    if (idx < NN * 32) {
        int row = idx >> 5;
        float n = norm[row];
        float4 v = x4[idx];
        int w = __builtin_amdgcn_cvt_pk_fp8_f32(v.x * n, v.y * n, 0, 0);
        w = __builtin_amdgcn_cvt_pk_fp8_f32(v.z * n, v.w * n, w, 1);
        g[idx] = w;
    }
}

// ---------------- CSR gather on fp8 rows, 4x16 lane layout (FROZEN, R7) -------
// One wave per node. lane = e*16 + c: 4 edge slots x 16 col-chunks of 8B.
// Measured 58.3us at VGPR 24 / occ 70%. R7 PMC: VALUBusy 54, HBM 37%,
// content 7.0 TB/s -> memory-system throughput wall; VALU cuts are exhausted.
// csr index prefetch (R6) + norm hoist (R4) retained. VGPR budget <=32 (R5).
template <int FINAL>
__global__ __launch_bounds__(256) void gather_fp8(const int* __restrict__ rowptr,
                                                  const int* __restrict__ csr,  // <<7
                                                  const char* __restrict__ hs,
                                                  const float* __restrict__ norm,
                                                  char* __restrict__ outv, float post) {
    int node = blockIdx.x * 4 + (threadIdx.x >> 6);
    int lane = threadIdx.x & 63;
    int e = lane >> 4;          // 4 edge slots
    int c = lane & 15;          // 16 col-chunks of 8 B
    int p0 = rowptr[node], p1 = rowptr[node + 1];
    float nrm = norm[node];     // hoisted: latency hides under the edge loop
    v2f acc[4];
#pragma unroll
    for (int i = 0; i < 4; ++i) acc[i] = (v2f)(0.0f);
    int coff8 = c << 3;
    int p = p0 + e;
#define CVT_ACC(v) { \
        acc[0] += __builtin_amdgcn_cvt_pk_f32_fp8((v).x, 0); \
        acc[1] += __builtin_amdgcn_cvt_pk_f32_fp8((v).x, 1); \
        acc[2] += __builtin_amdgcn_cvt_pk_f32_fp8((v).y, 0); \
        acc[3] += __builtin_amdgcn_cvt_pk_f32_fp8((v).y, 1); }
    int s0 = 0, s1 = 0, s2 = 0, s3 = 0;
    if (p + 12 < p1) { s0 = csr[p]; s1 = csr[p + 4]; s2 = csr[p + 8]; s3 = csr[p + 12]; }
    while (p + 12 < p1) {
        int2 v0 = *(const int2*)(hs + (unsigned)s0 + coff8);
        int2 v1 = *(const int2*)(hs + (unsigned)s1 + coff8);
        int2 v2 = *(const int2*)(hs + (unsigned)s2 + coff8);
        int2 v3 = *(const int2*)(hs + (unsigned)s3 + coff8);
        p += 16;
        if (p + 12 < p1) {          // prefetch next iteration's indices
            s0 = csr[p]; s1 = csr[p + 4]; s2 = csr[p + 8]; s3 = csr[p + 12];
        }
        CVT_ACC(v0);
        CVT_ACC(v1);
        CVT_ACC(v2);
        CVT_ACC(v3);
    }
    // 2-deep tail
    for (; p + 4 < p1; p += 8) {
        int t0 = csr[p];
        int t1 = csr[p + 4];
        int2 v0 = *(const int2*)(hs + (unsigned)t0 + coff8);
        int2 v1 = *(const int2*)(hs + (unsigned)t1 + coff8);
        CVT_ACC(v0);
        CVT_ACC(v1);
    }
    if (p < p1) {
        int t0 = csr[p];
        int2 v0 = *(const int2*)(hs + (unsigned)t0 + coff8);
        CVT_ACC(v0);
    }
#undef CVT_ACC
    // reduce over the 4 edge slots: stages 16 and 32
#pragma unroll
    for (int off = 16; off < 64; off <<= 1) {
#pragma unroll
        for (int i = 0; i < 4; ++i) {
            acc[i].x += __shfl_xor(acc[i].x, off, 64);
            acc[i].y += __shfl_xor(acc[i].y, off, 64);
        }
    }
    if (e == 0) {                 // lanes 0..15 write one int2 each = 128 B row
        float m = (FINAL ? nrm : nrm * nrm) * post;
        int2 w;
        w.x = __builtin_amdgcn_cvt_pk_fp8_f32(acc[0].x * m, acc[0].y * m, 0, 0);
        w.x = __builtin_amdgcn_cvt_pk_fp8_f32(acc[1].x * m, acc[1].y * m, w.x, 1);
        w.y = __builtin_amdgcn_cvt_pk_fp8_f32(acc[2].x * m, acc[2].y * m, 0, 0);
        w.y = __builtin_amdgcn_cvt_pk_fp8_f32(acc[3].x * m, acc[3].y * m, w.y, 1);
        *(int2*)(outv + (unsigned)node * 128 + coff8) = w;
    }
}

// ------- fp8 MFMA GEMM1: out_fp8 = fp8(relu(acc*PRE1 + b1) * norm * SCALE_G) --
__global__ __launch_bounds__(256) void gemm1_mfma(const char* __restrict__ H8,
                                                  const char* __restrict__ Wt8,
                                                  const float* __restrict__ b,
                                                  const float* __restrict__ norm,
                                                  char* __restrict__ out8) {
    int lane = threadIdx.x & 63;
    int w = threadIdx.x >> 6;
    int m = lane & 31;
    int q = lane >> 5;
    int col = w * 32 + m;
    long bf[8];
    const long* wp = (const long*)(Wt8 + (size_t)col * D + q * 8);
#pragma unroll
    for (int kc = 0; kc < 8; ++kc) bf[kc] = wp[kc * 2];
    float bc = b[col];
    for (int s = blockIdx.x; s < NSTRIP; s += gridDim.x) {
        int r0 = s * 32;
        floatx16 acc;
#pragma unroll
        for (int i = 0; i < 16; ++i) acc[i] = 0.0f;
        const long* ap = (const long*)(H8 + (size_t)(r0 + m) * D + q * 8);
#pragma unroll
        for (int kc = 0; kc < 8; ++kc)
            acc = __builtin_amdgcn_mfma_f32_32x32x16_fp8_fp8(ap[kc * 2], bf[kc], acc, 0, 0, 0);
#pragma unroll
        for (int r = 0; r < 16; ++r) {
            int row = r0 + (r & 3) + 8 * (r >> 2) + 4 * q;
            float v = fmaxf(acc[r] * PRE1 + bc, 0.0f) * norm[row] * SCALE_G;
            int pk = __builtin_amdgcn_cvt_pk_fp8_f32(v, v, 0, 0);
            out8[(size_t)row * D + col] = (char)(pk & 0xff);
        }
    }
}

// ------- fp8 MFMA GEMM2 + fused final MLP (R8: last-ticket pattern) -----------
__global__ __launch_bounds__(256) void gemm2_mfma_colsum(const char* __restrict__ H8,
                                                         const char* __restrict__ Wt8,
                                                         const float* __restrict__ b,
                                                         float* __restrict__ colsum,
                                                         int* __restrict__ done,
                                                         const float* __restrict__ Wf1,
                                                         const float* __restrict__ bf1,
                                                         const float* __restrict__ Wf2,
                                                         const float* __restrict__ bf2,
                                                         float* __restrict__ out) {
    int lane = threadIdx.x & 63;
    int w = threadIdx.x >> 6;
    int m = lane & 31;
    int q = lane >> 5;
    int col = w * 32 + m;
    long bf[8];
    const long* wp = (const long*)(Wt8 + (size_t)col * D + q * 8);
#pragma unroll
    for (int kc = 0; kc < 8; ++kc) bf[kc] = wp[kc * 2];
    float bc = b[col];
    float csum = 0.0f;
    for (int s = blockIdx.x; s < NSTRIP; s += gridDim.x) {
        int r0 = s * 32;
        floatx16 acc;
#pragma unroll
        for (int i = 0; i < 16; ++i) acc[i] = 0.0f;
        const long* ap = (const long*)(H8 + (size_t)(r0 + m) * D + q * 8);
#pragma unroll
        for (int kc = 0; kc < 8; ++kc)
            acc = __builtin_amdgcn_mfma_f32_32x32x16_fp8_fp8(ap[kc * 2], bf[kc], acc, 0, 0, 0);
#pragma unroll
        for (int r = 0; r < 16; ++r) csum += fmaxf(acc[r] * PRE2 + bc, 0.0f);
    }
    csum += __shfl_down(csum, 32);
    if (lane < 32) atomicAdd(&colsum[col], csum);

    // ---- last-ticket: one block runs the final MLP ----
    __threadfence();                         // release colsum adds
    __shared__ int isLast;
    if (threadIdx.x == 0)
        isLast = (atomicAdd(done, 1) == GRID_G2 - 1);
    __syncthreads();
    if (!isLast) return;

    __shared__ float hg[D];
    __shared__ float red[D];
    int j = threadIdx.x;
    if (j < D) hg[j] = atomicAdd(&colsum[j], 0.0f) * (1.0f / (float)NN);
    __syncthreads();
    if (j < D) {
        float acc2 = bf1[j];
#pragma unroll 16
        for (int k = 0; k < D; ++k)
            acc2 = fmaf(hg[k], Wf1[k * D + j], acc2);
        acc2 = fmaxf(acc2, 0.0f);
        red[j] = acc2 * Wf2[j];
    }
    __syncthreads();
    for (int s = 64; s > 0; s >>= 1) {
        if (j < s) red[j] += red[j + s];
        __syncthreads();
    }
    if (j == 0) {
        float o = red[0] + bf2[0];
        o = fmaxf(o, 0.0f);
        out[0] = 1.0f / (1.0f + expf(-o));
    }
}

// ---------------- launch ------------------------------------------------------
extern "C" void kernel_launch(void* const* d_in, const int* in_sizes, int n_in,
                              void* d_out, int out_size, void* d_ws, size_t ws_size,
                              hipStream_t stream) {
    const float* x   = (const float*)d_in[0];
    const int*   src = (const int*)d_in[1];
    const int*   dst = (const int*)d_in[2];
    const float* W1  = (const float*)d_in[3];
    const float* b1  = (const float*)d_in[4];
    const float* W2  = (const float*)d_in[5];
    const float* b2  = (const float*)d_in[6];
    const float* Wf1 = (const float*)d_in[7];
    const float* bf1 = (const float*)d_in[8];
    const float* Wf2 = (const float*)d_in[9];
    const float* bf2 = (const float*)d_in[10];
    float* out = (float*)d_out;

    char* ws = (char*)d_ws;
    constexpr size_t OFF_BT   = 0;                              // NB ints
    constexpr size_t OFF_CO   = 2048;                           // NB+1 ints
    constexpr size_t OFF_CS   = 4096;                           // colsum (+done ctr)
    constexpr size_t OFF_WT1  = 8192;                           // 16 KB fp8
    constexpr size_t OFF_WT2  = OFF_WT1 + 16384;
    constexpr size_t OFF_RP   = OFF_WT2 + 16384;                // NN+1 ints
    constexpr size_t OFF_NORM = OFF_RP + 400128;
    constexpr size_t OFF_BH   = OFF_NORM + 400128;              // NB*NBLK2 ints (400 KB)
    constexpr size_t OFF_EBUF = OFF_BH + (size_t)NB * NBLK2 * 4;// EE ints (12.8 MB, packed)
    constexpr size_t OFF_CSR  = OFF_EBUF + (size_t)EE * 8;      // EE ints (12.8 MB)
    constexpr size_t OFF_A8   = OFF_CSR + (size_t)EE * 4;       // NN*D fp8 (12.8 MB)
    constexpr size_t OFF_B8   = OFF_A8 + (size_t)NN * D;        // NN*D fp8
    int*    bintot = (int*)(ws + OFF_BT);
    int*    coff   = (int*)(ws + OFF_CO);
    float*  colsum = (float*)(ws + OFF_CS);
    int*    done   = (int*)(ws + OFF_CS + 512);                 // ticket counter
    char*   Wt1    = ws + OFF_WT1;
    char*   Wt2    = ws + OFF_WT2;
    int*    rowptr = (int*)(ws + OFF_RP);
    float*  norm   = (float*)(ws + OFF_NORM);
    int*    bh     = (int*)(ws + OFF_BH);
    int*    ebuf   = (int*)(ws + OFF_EBUF);
    int*    csr    = (int*)(ws + OFF_CSR);
    char*   bufA8  = ws + OFF_A8;
    char*   bufB8  = ws + OFF_B8;

    const int nT = 256;
    const int gridC = (NN * 32 + nT - 1) / nT;
    const int gridG = NN / 4;   // one wave per node, 4 waves/block

    // ---- CSR build + norm (no global atomics) ----
    block_hist<<<NBLK2, 1024, 0, stream>>>(dst, bh);
    bin_scan<<<NB, 256, 0, stream>>>(bh, bintot);
    tiny_scan<<<1, 512, 0, stream>>>(bintot, coff);
    scatter2<<<NBLK2, 1024, 0, stream>>>(src, dst, bh, coff, ebuf);
    fine_sort<<<NB, 256, 0, stream>>>(ebuf, coff, rowptr, norm, csr);

    // ---- weight prep (fp8, transposed, x16), both weights in one kernel ----
    conv_w2_fp8<<<64, 256, 0, stream>>>(W1, W2, Wt1, Wt2);

    // ---- propagation block 1 (fp8 rows, cumulative x6 per round) ----
    convert_scale_fp8<<<gridC, nT, 0, stream>>>((const float4*)x, (int*)bufA8, norm);
    gather_fp8<0><<<gridG, 256, 0, stream>>>(rowptr, csr, bufA8, norm, bufB8, SCALE_R);
    gather_fp8<0><<<gridG, 256, 0, stream>>>(rowptr, csr, bufB8, norm, bufA8, SCALE_R);
    gather_fp8<1><<<gridG, 256, 0, stream>>>(rowptr, csr, bufA8, norm, bufB8, SCALE_R);
    // bufB8 = h * 216 (fp8)

    // ---- g = fp8(relu(h @ W1 + b1) * norm * SCALE_G) : B -> A (fp8 MFMA) ----
    gemm1_mfma<<<625, 256, 0, stream>>>(bufB8, Wt1, b1, norm, bufA8);

    // ---- propagation block 2 ----
    gather_fp8<0><<<gridG, 256, 0, stream>>>(rowptr, csr, bufA8, norm, bufB8, SCALE_R);
    gather_fp8<0><<<gridG, 256, 0, stream>>>(rowptr, csr, bufB8, norm, bufA8, SCALE_R);
    gather_fp8<1><<<gridG, 256, 0, stream>>>(rowptr, csr, bufA8, norm, bufB8, SCALE_R);
    // bufB8 = h2 * 512 * 216 (fp8)

    // ---- colsum of relu(h2 @ W2 + b2) + fused final MLP (fp8 MFMA) ----
    hipMemsetAsync(colsum, 0, 768, stream);   // zeroes colsum[128] + done ctr
    gemm2_mfma_colsum<<<GRID_G2, 256, 0, stream>>>(bufB8, Wt2, b2, colsum, done,
                                                   Wf1, bf1, Wf2, bf2, out);
}

// Round 16
// 580.239 us; speedup vs baseline: 1.0283x; 1.0017x over previous
//
#include <hip/hip_runtime.h>
#include <hip/hip_fp16.h>
#include <math.h>

#define NN 100000
#define EE 3200000
#define D 128
#define NB 391        // coarse buckets: node>>8
#define NBLK2 256     // 256 segment-owners -> 128B segments (R10 line-touch fix)
#define ECH2 (EE / NBLK2)   // 12500 edges per block (exact)
#define NSTRIP (NN / 32)
#define FS_CAP 14336  // fine_sort LDS staging capacity (56 KB of packed ints)
#define GRID_G2 250   // gemm2 grid (last-ticket fusion constant)

#define WSCALE  16.0f     // weight fp8 scale (avoid subnormals)
// LIVE chain is the PROVEN R11 all-fp8 pipeline (581us): conv x1, gathers
// post x6 (S=216), gemm1 pre 1/(216*16) then x512, gathers x6, gemm2 pre
// 1/(216*512*16). fp4 kernels run only as CANARIES into dead buffers.
#define PRE1C (1.0f / 3456.0f)
#define SG1   512.0f
#define PRE2C (1.0f / 1769472.0f)

// fp4 canary guard (R14 proved this passes on the toolchain).
#if defined(__has_builtin)
#if __has_builtin(__builtin_amdgcn_cvt_scalef32_pk_fp4_f32) && \
    __has_builtin(__builtin_amdgcn_cvt_scalef32_pk_f32_fp4)
#define HAS_FP4 1
#else
#define HAS_FP4 0
#endif
#else
#define HAS_FP4 0
#endif

typedef float floatx16 __attribute__((ext_vector_type(16)));
typedef float v2f __attribute__((ext_vector_type(2)));

// ---------------- build pass 1: per-block histogram (transposed store) --------
__global__ __launch_bounds__(1024) void block_hist(const int* __restrict__ dst,
                                                   int* __restrict__ bh) {
    __shared__ int hist[NB];
    for (int i = threadIdx.x; i < NB; i += 1024) hist[i] = 0;
    __syncthreads();
    int e0 = blockIdx.x * ECH2;
    for (int e = e0 + threadIdx.x; e < e0 + ECH2; e += 1024)
        atomicAdd(&hist[dst[e] >> 8], 1);
    __syncthreads();
    for (int i = threadIdx.x; i < NB; i += 1024)
        bh[i * NBLK2 + blockIdx.x] = hist[i];
}

// ---------------- build pass 2: per-bin exclusive scan over blocks ------------
__global__ __launch_bounds__(256) void bin_scan(int* __restrict__ bh,
                                                int* __restrict__ bintot) {
    __shared__ int ts[256];
    int i = blockIdx.x;      // bucket
    int t = threadIdx.x;     // block index within bucket
    int v = bh[i * NBLK2 + t];
    ts[t] = v;
    __syncthreads();
    for (int off = 1; off < 256; off <<= 1) {
        int x = (t >= off) ? ts[t - off] : 0;
        __syncthreads();
        ts[t] += x;
        __syncthreads();
    }
    bh[i * NBLK2 + t] = ts[t] - v;   // exclusive
    if (t == 255) bintot[i] = ts[255];
}

// ---------------- build pass 3: exclusive scan of bin totals -> coff ----------
__global__ __launch_bounds__(512) void tiny_scan(const int* __restrict__ bintot,
                                                 int* __restrict__ coff) {
    __shared__ int s[512];
    int t = threadIdx.x;
    int v = (t < NB) ? bintot[t] : 0;
    s[t] = v;
    __syncthreads();
    for (int off = 1; off < 512; off <<= 1) {
        int x = (t >= off) ? s[t - off] : 0;
        __syncthreads();
        s[t] += x;
        __syncthreads();
    }
    int excl = s[t] - v;
    if (t <= NB) coff[t] = excl;   // coff[NB] == EE
}

// ---------------- build pass 4: scatter with precomputed bases ----------------
// Packed 4B entries: (src<<8) | (dst&255). 128B segments + 16 waves/block.
__global__ __launch_bounds__(1024) void scatter2(const int* __restrict__ src,
                                                 const int* __restrict__ dst,
                                                 const int* __restrict__ bh,
                                                 const int* __restrict__ coff,
                                                 int* __restrict__ ebuf) {
    __shared__ int base[NB];
    int b = blockIdx.x;
    for (int i = threadIdx.x; i < NB; i += 1024)
        base[i] = coff[i] + bh[i * NBLK2 + b];
    __syncthreads();
    int e0 = b * ECH2;
    for (int e = e0 + threadIdx.x; e < e0 + ECH2; e += 1024) {
        int d = dst[e];
        int pos = atomicAdd(&base[d >> 8], 1);
        ebuf[pos] = (src[e] << 8) | (d & 255);
    }
}

// ---------------- build pass 5: per-bucket fine sort -> rowptr/norm/csr -------
// csr entries pre-shifted <<6 (byte offset of a 64B fp4 row); fp8 readers <<1.
__global__ __launch_bounds__(256) void fine_sort(const int* __restrict__ ebuf,
                                                 const int* __restrict__ coarse_off,
                                                 int* __restrict__ rowptr,
                                                 float* __restrict__ norm,
                                                 int* __restrict__ csr) {
    __shared__ int cnt[256];
    __shared__ int sbuf[256];
    __shared__ int es[FS_CAP];   // 56 KB staging (packed ints)
    int b = blockIdx.x;
    int t = threadIdx.x;
    int e0 = coarse_off[b], e1 = coarse_off[b + 1];
    int n = e1 - e0;
    int nl = n < FS_CAP ? n : FS_CAP;
    int n0 = b << 8;
    cnt[t] = 0;
    __syncthreads();
    for (int i = t; i < nl; i += 256) {
        int pv = ebuf[e0 + i];
        es[i] = pv;
        atomicAdd(&cnt[pv & 255], 1);
    }
    for (int i = FS_CAP + t; i < n; i += 256) {        // overflow tail
        int pv = ebuf[e0 + i];
        atomicAdd(&cnt[pv & 255], 1);
    }
    __syncthreads();
    int myc = cnt[t];
    sbuf[t] = myc;
    __syncthreads();
    for (int off = 1; off < 256; off <<= 1) {
        int x = (t >= off) ? sbuf[t - off] : 0;
        __syncthreads();
        sbuf[t] += x;
        __syncthreads();
    }
    int excl = sbuf[t] - myc;
    int node = n0 + t;
    if (node < NN) {
        rowptr[node] = e0 + excl;
        float dd = (float)myc;
        if (dd < 1.0f) dd = 1.0f;
        norm[node] = rsqrtf(dd);
    }
    cnt[t] = e0 + excl;
    __syncthreads();
    for (int i = t; i < nl; i += 256) {                // from LDS, not global
        int pv = es[i];
        int pos = atomicAdd(&cnt[pv & 255], 1);
        csr[pos] = (pv >> 8) << 6;                     // src*64 byte offset
    }
    for (int i = FS_CAP + t; i < n; i += 256) {        // overflow tail
        int pv = __builtin_nontemporal_load(ebuf + e0 + i);
        int pos = atomicAdd(&cnt[pv & 255], 1);
        csr[pos] = (pv >> 8) << 6;
    }
    if (b == 0 && t == 0) rowptr[NN] = EE;
}

// --- weight convert + transpose to fp8, BOTH weights in one kernel ------------
__global__ void conv_w2_fp8(const float* __restrict__ W1, const float* __restrict__ W2,
                            char* __restrict__ Wt1, char* __restrict__ Wt2) {
    int g = blockIdx.x;
    const float* W = (g < 32) ? W1 : W2;
    char* Wt8 = (g < 32) ? Wt1 : Wt2;
    int idx = (g & 31) * 256 + threadIdx.x;
    if (idx < D * D / 2) {
        int n = idx >> 6, k2 = (idx & 63) * 2;
        float a = W[k2 * D + n] * WSCALE;
        float b = W[(k2 + 1) * D + n] * WSCALE;
        int pk = __builtin_amdgcn_cvt_pk_fp8_f32(a, b, 0, 0);
        ((short*)Wt8)[idx] = (short)(pk & 0xffff);
    }
}

// ---------------- convert+scale: fp8 (live chain) ----------------
__global__ void convert_scale_fp8(const float4* __restrict__ x4, int* __restrict__ g,
                                  const float* __restrict__ norm) {
    int idx = blockIdx.x * 256 + threadIdx.x;   // NN*32 threads, 4 cols each
    if (idx < NN * 32) {
        int row = idx >> 5;
        float n = norm[row];
        float4 v = x4[idx];
        int w = __builtin_amdgcn_cvt_pk_fp8_f32(v.x * n, v.y * n, 0, 0);
        w = __builtin_amdgcn_cvt_pk_fp8_f32(v.z * n, v.w * n, w, 1);
        g[idx] = w;
    }
}

#if HAS_FP4
// ---------------- convert+scale: fp4 (canary) ----------------
__global__ void convert_scale_fp4(const float4* __restrict__ x4,
                                  unsigned* __restrict__ g,
                                  const float* __restrict__ norm) {
    int idx = blockIdx.x * 256 + threadIdx.x;   // NN*16 threads, 8 cols each
    if (idx < NN * 16) {
        int row = idx >> 4;
        float n = norm[row] * 8.0f;
        float4 a = x4[idx * 2];
        float4 b = x4[idx * 2 + 1];
        unsigned u = 0;
        u = __builtin_amdgcn_cvt_scalef32_pk_fp4_f32(u, a.x * n, a.y * n, 1.0f, 0);
        u = __builtin_amdgcn_cvt_scalef32_pk_fp4_f32(u, a.z * n, a.w * n, 1.0f, 1);
        u = __builtin_amdgcn_cvt_scalef32_pk_fp4_f32(u, b.x * n, b.y * n, 1.0f, 2);
        u = __builtin_amdgcn_cvt_scalef32_pk_fp4_f32(u, b.z * n, b.w * n, 1.0f, 3);
        g[idx] = u;
    }
}
#endif

// ---------------- CSR gather, mixed fp4/fp8 rows ----------------
// One wave per node; lane = e*16 + c (4 edge slots x 16 col-chunks).
// IN8: 128B fp8 rows (csr<<1); else 64B fp4 rows. OUT8: fp8/fp4 row out.
// FINAL: m = nrm*post vs nrm*nrm*post.
// R5 VGPR budget (<=32), R6 csr prefetch, R4 norm hoist retained.
template <int IN8, int OUT8, int FINAL>
__global__ __launch_bounds__(256) void gather_mix(const int* __restrict__ rowptr,
                                                  const int* __restrict__ csr,  // <<6
                                                  const char* __restrict__ hs,
                                                  const float* __restrict__ norm,
                                                  char* __restrict__ outv, float post) {
    int node = blockIdx.x * 4 + (threadIdx.x >> 6);
    int lane = threadIdx.x & 63;
    int e = lane >> 4;          // 4 edge slots
    int c = lane & 15;          // 16 col-chunks
    int p0 = rowptr[node], p1 = rowptr[node + 1];
    float nrm = norm[node];     // hoisted
    v2f acc[4];
#pragma unroll
    for (int i = 0; i < 4; ++i) acc[i] = (v2f)(0.0f);
    int p = p0 + e;
    int s0 = 0, s1 = 0, s2 = 0, s3 = 0;
    if (p + 12 < p1) { s0 = csr[p]; s1 = csr[p + 4]; s2 = csr[p + 8]; s3 = csr[p + 12]; }
#define CVT8(v) { \
        acc[0] += __builtin_amdgcn_cvt_pk_f32_fp8((v).x, 0); \
        acc[1] += __builtin_amdgcn_cvt_pk_f32_fp8((v).x, 1); \
        acc[2] += __builtin_amdgcn_cvt_pk_f32_fp8((v).y, 0); \
        acc[3] += __builtin_amdgcn_cvt_pk_f32_fp8((v).y, 1); }
#if HAS_FP4
// unpack builtin returns a GCC __vector_size__ float2 — [] indexing only.
#define CVT4(v) { \
        { auto r = __builtin_amdgcn_cvt_scalef32_pk_f32_fp4((v), 1.0f, 0); acc[0].x += r[0]; acc[0].y += r[1]; } \
        { auto r = __builtin_amdgcn_cvt_scalef32_pk_f32_fp4((v), 1.0f, 1); acc[1].x += r[0]; acc[1].y += r[1]; } \
        { auto r = __builtin_amdgcn_cvt_scalef32_pk_f32_fp4((v), 1.0f, 2); acc[2].x += r[0]; acc[2].y += r[1]; } \
        { auto r = __builtin_amdgcn_cvt_scalef32_pk_f32_fp4((v), 1.0f, 3); acc[3].x += r[0]; acc[3].y += r[1]; } }
#else
#define CVT4(v) {}
#endif
    if (IN8) {
        int coff = c << 3;
        while (p + 12 < p1) {
            int2 v0 = *(const int2*)(hs + (((unsigned)s0) << 1) + coff);
            int2 v1 = *(const int2*)(hs + (((unsigned)s1) << 1) + coff);
            int2 v2 = *(const int2*)(hs + (((unsigned)s2) << 1) + coff);
            int2 v3 = *(const int2*)(hs + (((unsigned)s3) << 1) + coff);
            p += 16;
            if (p + 12 < p1) { s0 = csr[p]; s1 = csr[p + 4]; s2 = csr[p + 8]; s3 = csr[p + 12]; }
            CVT8(v0); CVT8(v1); CVT8(v2); CVT8(v3);
        }
        for (; p + 4 < p1; p += 8) {
            int t0 = csr[p];
            int t1 = csr[p + 4];
            int2 v0 = *(const int2*)(hs + (((unsigned)t0) << 1) + coff);
            int2 v1 = *(const int2*)(hs + (((unsigned)t1) << 1) + coff);
            CVT8(v0); CVT8(v1);
        }
        if (p < p1) {
            int t0 = csr[p];
            int2 v0 = *(const int2*)(hs + (((unsigned)t0) << 1) + coff);
            CVT8(v0);
        }
    } else {
        int coff = c << 2;
        while (p + 12 < p1) {
            unsigned v0 = *(const unsigned*)(hs + (unsigned)s0 + coff);
            unsigned v1 = *(const unsigned*)(hs + (unsigned)s1 + coff);
            unsigned v2 = *(const unsigned*)(hs + (unsigned)s2 + coff);
            unsigned v3 = *(const unsigned*)(hs + (unsigned)s3 + coff);
            p += 16;
            if (p + 12 < p1) { s0 = csr[p]; s1 = csr[p + 4]; s2 = csr[p + 8]; s3 = csr[p + 12]; }
            CVT4(v0); CVT4(v1); CVT4(v2); CVT4(v3);
        }
        for (; p + 4 < p1; p += 8) {
            int t0 = csr[p];
            int t1 = csr[p + 4];
            unsigned v0 = *(const unsigned*)(hs + (unsigned)t0 + coff);
            unsigned v1 = *(const unsigned*)(hs + (unsigned)t1 + coff);
            CVT4(v0); CVT4(v1);
        }
        if (p < p1) {
            int t0 = csr[p];
            unsigned v0 = *(const unsigned*)(hs + (unsigned)t0 + coff);
            CVT4(v0);
        }
    }
#undef CVT8
#undef CVT4
    // reduce over the 4 edge slots: stages 16 and 32
#pragma unroll
    for (int off = 16; off < 64; off <<= 1) {
#pragma unroll
        for (int i = 0; i < 4; ++i) {
            acc[i].x += __shfl_xor(acc[i].x, off, 64);
            acc[i].y += __shfl_xor(acc[i].y, off, 64);
        }
    }
    if (e == 0) {
        float m = (FINAL ? nrm : nrm * nrm) * post;
        if (OUT8) {               // fp8 128B row
            int2 w;
            w.x = __builtin_amdgcn_cvt_pk_fp8_f32(acc[0].x * m, acc[0].y * m, 0, 0);
            w.x = __builtin_amdgcn_cvt_pk_fp8_f32(acc[1].x * m, acc[1].y * m, w.x, 1);
            w.y = __builtin_amdgcn_cvt_pk_fp8_f32(acc[2].x * m, acc[2].y * m, 0, 0);
            w.y = __builtin_amdgcn_cvt_pk_fp8_f32(acc[3].x * m, acc[3].y * m, w.y, 1);
            *(int2*)(outv + (unsigned)node * 128 + (c << 3)) = w;
        } else {                  // fp4 64B row
#if HAS_FP4
            unsigned u = 0;
            u = __builtin_amdgcn_cvt_scalef32_pk_fp4_f32(u, acc[0].x * m, acc[0].y * m, 1.0f, 0);
            u = __builtin_amdgcn_cvt_scalef32_pk_fp4_f32(u, acc[1].x * m, acc[1].y * m, 1.0f, 1);
            u = __builtin_amdgcn_cvt_scalef32_pk_fp4_f32(u, acc[2].x * m, acc[2].y * m, 1.0f, 2);
            u = __builtin_amdgcn_cvt_scalef32_pk_fp4_f32(u, acc[3].x * m, acc[3].y * m, 1.0f, 3);
            *(unsigned*)(outv + (unsigned)node * 64 + (c << 2)) = u;
#endif
        }
    }
}

// ------- fp8 MFMA GEMM1: out_fp8 = fp8(relu(acc*PRE1C + b1) * norm * 512) -----
__global__ __launch_bounds__(256) void gemm1_mfma(const char* __restrict__ H8,
                                                  const char* __restrict__ Wt8,
                                                  const float* __restrict__ b,
                                                  const float* __restrict__ norm,
                                                  char* __restrict__ out8) {
    int lane = threadIdx.x & 63;
    int w = threadIdx.x >> 6;
    int m = lane & 31;
    int q = lane >> 5;
    int col = w * 32 + m;
    long bf[8];
    const long* wp = (const long*)(Wt8 + (size_t)col * D + q * 8);
#pragma unroll
    for (int kc = 0; kc < 8; ++kc) bf[kc] = wp[kc * 2];
    float bc = b[col];
    for (int s = blockIdx.x; s < NSTRIP; s += gridDim.x) {
        int r0 = s * 32;
        floatx16 acc;
#pragma unroll
        for (int i = 0; i < 16; ++i) acc[i] = 0.0f;
        const long* ap = (const long*)(H8 + (size_t)(r0 + m) * D + q * 8);
#pragma unroll
        for (int kc = 0; kc < 8; ++kc)
            acc = __builtin_amdgcn_mfma_f32_32x32x16_fp8_fp8(ap[kc * 2], bf[kc], acc, 0, 0, 0);
#pragma unroll
        for (int r = 0; r < 16; ++r) {
            int row = r0 + (r & 3) + 8 * (r >> 2) + 4 * q;
            float v = fmaxf(acc[r] * PRE1C + bc, 0.0f) * norm[row] * SG1;
            int pk = __builtin_amdgcn_cvt_pk_fp8_f32(v, v, 0, 0);
            out8[(size_t)row * D + col] = (char)(pk & 0xff);
        }
    }
}

// ------- fp8 MFMA GEMM2 + fused final MLP (last-ticket pattern) ---------------
__global__ __launch_bounds__(256) void gemm2_mfma_colsum(const char* __restrict__ H8,
                                                         const char* __restrict__ Wt8,
                                                         const float* __restrict__ b,
                                                         float* __restrict__ colsum,
                                                         int* __restrict__ done,
                                                         const float* __restrict__ Wf1,
                                                         const float* __restrict__ bf1,
                                                         const float* __restrict__ Wf2,
                                                         const float* __restrict__ bf2,
                                                         float* __restrict__ out) {
    int lane = threadIdx.x & 63;
    int w = threadIdx.x >> 6;
    int m = lane & 31;
    int q = lane >> 5;
    int col = w * 32 + m;
    long bf[8];
    const long* wp = (const long*)(Wt8 + (size_t)col * D + q * 8);
#pragma unroll
    for (int kc = 0; kc < 8; ++kc) bf[kc] = wp[kc * 2];
    float bc = b[col];
    float csum = 0.0f;
    for (int s = blockIdx.x; s < NSTRIP; s += gridDim.x) {
        int r0 = s * 32;
        floatx16 acc;
#pragma unroll
        for (int i = 0; i < 16; ++i) acc[i] = 0.0f;
        const long* ap = (const long*)(H8 + (size_t)(r0 + m) * D + q * 8);
#pragma unroll
        for (int kc = 0; kc < 8; ++kc)
            acc = __builtin_amdgcn_mfma_f32_32x32x16_fp8_fp8(ap[kc * 2], bf[kc], acc, 0, 0, 0);
#pragma unroll
        for (int r = 0; r < 16; ++r) csum += fmaxf(acc[r] * PRE2C + bc, 0.0f);
    }
    csum += __shfl_down(csum, 32);
    if (lane < 32) atomicAdd(&colsum[col], csum);

    // ---- last-ticket: one block runs the final MLP ----
    __threadfence();                         // release colsum adds
    __shared__ int isLast;
    if (threadIdx.x == 0)
        isLast = (atomicAdd(done, 1) == GRID_G2 - 1);
    __syncthreads();
    if (!isLast) return;

    __shared__ float hg[D];
    __shared__ float red[D];
    int j = threadIdx.x;
    if (j < D) hg[j] = atomicAdd(&colsum[j], 0.0f) * (1.0f / (float)NN);
    __syncthreads();
    if (j < D) {
        float acc2 = bf1[j];
#pragma unroll 16
        for (int k = 0; k < D; ++k)
            acc2 = fmaf(hg[k], Wf1[k * D + j], acc2);
        acc2 = fmaxf(acc2, 0.0f);
        red[j] = acc2 * Wf2[j];
    }
    __syncthreads();
    for (int s = 64; s > 0; s >>= 1) {
        if (j < s) red[j] += red[j + s];
        __syncthreads();
    }
    if (j == 0) {
        float o = red[0] + bf2[0];
        o = fmaxf(o, 0.0f);
        out[0] = 1.0f / (1.0f + expf(-o));
    }
}

// ---------------- launch ------------------------------------------------------
extern "C" void kernel_launch(void* const* d_in, const int* in_sizes, int n_in,
                              void* d_out, int out_size, void* d_ws, size_t ws_size,
                              hipStream_t stream) {
    const float* x   = (const float*)d_in[0];
    const int*   src = (const int*)d_in[1];
    const int*   dst = (const int*)d_in[2];
    const float* W1  = (const float*)d_in[3];
    const float* b1  = (const float*)d_in[4];
    const float* W2  = (const float*)d_in[5];
    const float* b2  = (const float*)d_in[6];
    const float* Wf1 = (const float*)d_in[7];
    const float* bf1 = (const float*)d_in[8];
    const float* Wf2 = (const float*)d_in[9];
    const float* bf2 = (const float*)d_in[10];
    float* out = (float*)d_out;

    char* ws = (char*)d_ws;
    constexpr size_t OFF_BT   = 0;                              // NB ints
    constexpr size_t OFF_CO   = 2048;                           // NB+1 ints
    constexpr size_t OFF_CS   = 4096;                           // colsum (+done ctr)
    constexpr size_t OFF_WT1  = 8192;                           // 16 KB fp8
    constexpr size_t OFF_WT2  = OFF_WT1 + 16384;
    constexpr size_t OFF_RP   = OFF_WT2 + 16384;                // NN+1 ints
    constexpr size_t OFF_NORM = OFF_RP + 400128;
    constexpr size_t OFF_BH   = OFF_NORM + 400128;              // NB*NBLK2 ints (400 KB)
    constexpr size_t OFF_EBUF = OFF_BH + (size_t)NB * NBLK2 * 4;// EE ints (12.8 MB)
    constexpr size_t OFF_CSR  = OFF_EBUF + (size_t)EE * 4;      // EE ints (12.8 MB)
    constexpr size_t OFF_A4   = OFF_CSR + (size_t)EE * 4;       // NN*64 fp4 canary
    constexpr size_t OFF_B4   = OFF_A4 + (size_t)NN * 64;       // NN*64 fp4 canary
    constexpr size_t OFF_F8   = OFF_B4 + (size_t)NN * 64;       // NN*128 fp8 (live A)
    constexpr size_t OFF_G8   = OFF_F8 + (size_t)NN * D;        // NN*128 fp8 (live B)
    int*    bintot = (int*)(ws + OFF_BT);
    int*    coff   = (int*)(ws + OFF_CO);
    float*  colsum = (float*)(ws + OFF_CS);
    int*    done   = (int*)(ws + OFF_CS + 512);                 // ticket counter
    char*   Wt1    = ws + OFF_WT1;
    char*   Wt2    = ws + OFF_WT2;
    int*    rowptr = (int*)(ws + OFF_RP);
    float*  norm   = (float*)(ws + OFF_NORM);
    int*    bh     = (int*)(ws + OFF_BH);
    int*    ebuf   = (int*)(ws + OFF_EBUF);
    int*    csr    = (int*)(ws + OFF_CSR);
    char*   bufA4  = ws + OFF_A4;
    char*   bufB4  = ws + OFF_B4;
    char*   bufF8  = ws + OFF_F8;
    char*   bufG8  = ws + OFF_G8;

    const int gridG = NN / 4;   // one wave per node, 4 waves/block

    // ---- CSR build + norm (no global atomics) ----
    block_hist<<<NBLK2, 1024, 0, stream>>>(dst, bh);
    bin_scan<<<NB, 256, 0, stream>>>(bh, bintot);
    tiny_scan<<<1, 512, 0, stream>>>(bintot, coff);
    scatter2<<<NBLK2, 1024, 0, stream>>>(src, dst, bh, coff, ebuf);
    fine_sort<<<NB, 256, 0, stream>>>(ebuf, coff, rowptr, norm, csr);

    // ---- weight prep (fp8, transposed, x16) ----
    conv_w2_fp8<<<64, 256, 0, stream>>>(W1, W2, Wt1, Wt2);

    // ---- LIVE: PROVEN R11 all-fp8 chain (F8 <-> G8 ping-pong) ----
    const int gridC8 = (NN * 32 + 255) / 256;
    convert_scale_fp8<<<gridC8, 256, 0, stream>>>((const float4*)x, (int*)bufF8, norm);
    gather_mix<1, 1, 0><<<gridG, 256, 0, stream>>>(rowptr, csr, bufF8, norm, bufG8, 6.0f);
    gather_mix<1, 1, 0><<<gridG, 256, 0, stream>>>(rowptr, csr, bufG8, norm, bufF8, 6.0f);
    gather_mix<1, 1, 1><<<gridG, 256, 0, stream>>>(rowptr, csr, bufF8, norm, bufG8, 6.0f);
    // bufG8 = h * 216 (fp8)
    gemm1_mfma<<<625, 256, 0, stream>>>(bufG8, Wt1, b1, norm, bufF8);
    gather_mix<1, 1, 0><<<gridG, 256, 0, stream>>>(rowptr, csr, bufF8, norm, bufG8, 6.0f);
    gather_mix<1, 1, 0><<<gridG, 256, 0, stream>>>(rowptr, csr, bufG8, norm, bufF8, 6.0f);
    gather_mix<1, 1, 1><<<gridG, 256, 0, stream>>>(rowptr, csr, bufF8, norm, bufG8, 6.0f);
    // bufG8 = h2 * 216*512 (fp8)
    hipMemsetAsync(colsum, 0, 768, stream);
    gemm2_mfma_colsum<<<GRID_G2, 256, 0, stream>>>(bufG8, Wt2, b2, colsum, done,
                                                   Wf1, bf1, Wf2, bf2, out);

#if HAS_FP4
    // ---- CANARIES (after the result is produced; outputs dead) ----
    // Exercises all fp4 kernels at full grid/address coverage AND measures
    // their timing in the dispatch table. If these fault, fp4 is convicted;
    // if they pass fast, R17 wires them live (~490us predicted).
    const int gridC4 = (NN * 16 + 255) / 256;
    convert_scale_fp4<<<gridC4, 256, 0, stream>>>((const float4*)x, (unsigned*)bufA4, norm);
    gather_mix<0, 0, 0><<<gridG, 256, 0, stream>>>(rowptr, csr, bufA4, norm, bufB4, 6.0f);
    gather_mix<0, 1, 1><<<gridG, 256, 0, stream>>>(rowptr, csr, bufB4, norm, bufF8, 2.0f);
    gather_mix<1, 0, 0><<<gridG, 256, 0, stream>>>(rowptr, csr, bufF8, norm, bufA4, 24.0f);
#endif
}